// Round 1
// baseline (94.542 us; speedup 1.0000x reference)
//
#include <hip/hip_runtime.h>

// FinalLayer: fused RBF-weighted interpolation + pointwise linear.
// Shapes: x(B,N_IN,1) y(B,N_IN,C) t(B,N_OUT,1) sigma(C) w(C,1) b(1)
// out(B,N_OUT,1) fp32, flat B*N_OUT.
constexpr int Bb   = 4;
constexpr int NIN  = 512;
constexpr int NOUT = 1024;
constexpr int CC   = 64;   // == wavefront size, lane = channel

constexpr int M_PER_WAVE      = 2;  // output points per wave (y-load reuse)
constexpr int WAVES_PER_BLOCK = 4;  // block = 256 threads

__global__ __launch_bounds__(256, 2) void rbf_fused(
    const float* __restrict__ x,     // (B, N_IN)
    const float* __restrict__ y,     // (B, N_IN, C)
    const float* __restrict__ t,     // (B, N_OUT)
    const float* __restrict__ sigma, // (C)
    const float* __restrict__ w,     // (C)
    const float* __restrict__ bias,  // (1)
    float* __restrict__ out)         // (B, N_OUT)
{
    const int lane    = threadIdx.x & 63;
    const int wave_id = blockIdx.x * WAVES_PER_BLOCK + (threadIdx.x >> 6);
    const int gm0     = wave_id * M_PER_WAVE;     // global flat output base
    const int b       = gm0 / NOUT;
    const int m0      = gm0 - b * NOUT;

    const int c = lane;
    // scales = exp(sigma); 1/scales^2 = exp(-2 sigma); kc = -0.5 * exp(-2 sigma)
    const float kc = -0.5f * __expf(-2.0f * sigma[c]);
    const float wc = w[c];

    const float t0 = t[b * NOUT + m0];
    const float t1 = t[b * NOUT + m0 + 1];

    const float* __restrict__ yb = y + (size_t)b * NIN * CC + c;
    const float* __restrict__ xb = x + b * NIN;

    float acc0 = 0.f, acc1 = 0.f;
#pragma unroll 8
    for (int n = 0; n < NIN; ++n) {
        const float xn = xb[n];            // lane-uniform broadcast
        const float yv = yb[(size_t)n * CC]; // coalesced 256B/wave
        const float d0 = xn - t0;
        const float d1 = xn - t1;
        acc0 += __expf(d0 * d0 * kc) * yv; // v_exp_f32 path
        acc1 += __expf(d1 * d1 * kc) * yv;
    }

    // pointwise linear over channels: butterfly reduce across the 64 lanes
    float p0 = acc0 * wc;
    float p1 = acc1 * wc;
#pragma unroll
    for (int off = 32; off > 0; off >>= 1) {
        p0 += __shfl_xor(p0, off, 64);
        p1 += __shfl_xor(p1, off, 64);
    }
    if (lane == 0) {
        const float bv = bias[0];
        out[gm0]     = p0 + bv;
        out[gm0 + 1] = p1 + bv;
    }
}

extern "C" void kernel_launch(void* const* d_in, const int* in_sizes, int n_in,
                              void* d_out, int out_size, void* d_ws, size_t ws_size,
                              hipStream_t stream) {
    const float* x     = (const float*)d_in[0];
    const float* y     = (const float*)d_in[1];
    const float* t     = (const float*)d_in[2];
    const float* sigma = (const float*)d_in[3];
    const float* w     = (const float*)d_in[4];
    const float* bias  = (const float*)d_in[5];
    float* out = (float*)d_out;

    const int total_out = Bb * NOUT;                              // 4096
    const int grid = total_out / (M_PER_WAVE * WAVES_PER_BLOCK);  // 512
    rbf_fused<<<grid, WAVES_PER_BLOCK * 64, 0, stream>>>(x, y, t, sigma, w, bias, out);
}

// Round 2
// 85.639 us; speedup vs baseline: 1.1040x; 1.1040x over previous
//
#include <hip/hip_runtime.h>

// FinalLayer: fused RBF-weighted interpolation + pointwise linear.
// out[b,m] = bias + sum_c w_c * sum_n y[b,n,c] * exp(-0.5*(x_n-t_m)^2 * exp(-2*sigma_c))
// Shapes: x(B,N_IN) y(B,N_IN,C) t(B,N_OUT) sigma(C) w(C) b(1); out flat B*N_OUT fp32.
constexpr int Bb   = 4;
constexpr int NIN  = 512;
constexpr int NOUT = 1024;
constexpr int CC   = 64;   // == wavefront size, lane = channel

constexpr int M_PER_WAVE      = 4;  // output points per wave (ILP + y-load reuse)
constexpr int NSPLIT          = 8;  // split-K over n for occupancy (atomic combine)
constexpr int WAVES_PER_BLOCK = 4;  // block = 256 threads
constexpr int NCHUNK          = NIN / NSPLIT;           // 64
constexpr int MG_PER_BATCH    = NOUT / M_PER_WAVE;      // 256
constexpr int BLK_PER_BS      = MG_PER_BATCH / WAVES_PER_BLOCK; // 64

__global__ __launch_bounds__(256, 8) void rbf_fused(
    const float* __restrict__ x,     // (B, N_IN)
    const float* __restrict__ y,     // (B, N_IN, C)
    const float* __restrict__ t,     // (B, N_OUT)
    const float* __restrict__ sigma, // (C)
    const float* __restrict__ w,     // (C)
    const float* __restrict__ bias,  // (1)
    float* __restrict__ out)         // (B, N_OUT) -- pre-zeroed, atomic accumulate
{
    const int lane  = threadIdx.x & 63;
    const int wv    = threadIdx.x >> 6;
    const int bi    = blockIdx.x;
    const int blk   = bi & (BLK_PER_BS - 1);         // 0..63
    const int split = (bi >> 6) & (NSPLIT - 1);      // 0..7
    const int b     = bi >> 9;                       // 0..3

    const int mg = blk * WAVES_PER_BLOCK + wv;       // 0..255 within batch
    const int m0 = mg * M_PER_WAVE;                  // 0..1020

    const int c = lane;
    // arg = (x-t)^2 * (-0.5 * exp(-2 sigma) * log2(e)); exp2 via HW instr
    const float kc2 = -0.72134752f * __expf(-2.0f * sigma[c]);
    const float wc  = w[c];

    const float* tb = t + b * NOUT + m0;
    const float t0 = tb[0], t1 = tb[1], t2 = tb[2], t3 = tb[3];

    const int n0 = split * NCHUNK;
    const float* __restrict__ xb = x + b * NIN + n0;                 // scalar loads
    const float* __restrict__ yb = y + ((size_t)b * NIN + n0) * CC + c;

    float a0 = 0.f, a1 = 0.f, a2 = 0.f, a3 = 0.f;
#pragma unroll 4
    for (int n = 0; n < NCHUNK; ++n) {
        const float xn = xb[n];               // wave/block-uniform -> s_load
        const float yv = yb[(size_t)n * CC];  // coalesced 256B/wave, L2-hot
        const float d0 = xn - t0;
        const float d1 = xn - t1;
        const float d2 = xn - t2;
        const float d3 = xn - t3;
        a0 += __builtin_amdgcn_exp2f(d0 * d0 * kc2) * yv;
        a1 += __builtin_amdgcn_exp2f(d1 * d1 * kc2) * yv;
        a2 += __builtin_amdgcn_exp2f(d2 * d2 * kc2) * yv;
        a3 += __builtin_amdgcn_exp2f(d3 * d3 * kc2) * yv;
    }

    // channel reduction (pointwise linear): butterfly across 64 lanes
    float p0 = a0 * wc, p1 = a1 * wc, p2 = a2 * wc, p3 = a3 * wc;
#pragma unroll
    for (int off = 32; off > 0; off >>= 1) {
        p0 += __shfl_xor(p0, off, 64);
        p1 += __shfl_xor(p1, off, 64);
        p2 += __shfl_xor(p2, off, 64);
        p3 += __shfl_xor(p3, off, 64);
    }
    if (lane == 0) {
        const float bv = (split == 0) ? bias[0] : 0.f;
        float* o = out + b * NOUT + m0;
        atomicAdd(o + 0, p0 + bv);
        atomicAdd(o + 1, p1 + bv);
        atomicAdd(o + 2, p2 + bv);
        atomicAdd(o + 3, p3 + bv);
    }
}

extern "C" void kernel_launch(void* const* d_in, const int* in_sizes, int n_in,
                              void* d_out, int out_size, void* d_ws, size_t ws_size,
                              hipStream_t stream) {
    const float* x     = (const float*)d_in[0];
    const float* y     = (const float*)d_in[1];
    const float* t     = (const float*)d_in[2];
    const float* sigma = (const float*)d_in[3];
    const float* w     = (const float*)d_in[4];
    const float* bias  = (const float*)d_in[5];
    float* out = (float*)d_out;

    // harness poisons d_out with 0xAA before each timed call -> zero it (async, capturable)
    hipMemsetAsync(out, 0, (size_t)out_size * sizeof(float), stream);

    const int grid = Bb * NSPLIT * BLK_PER_BS;  // 4*8*64 = 2048 blocks
    rbf_fused<<<grid, WAVES_PER_BLOCK * 64, 0, stream>>>(x, y, t, sigma, w, bias, out);
}

// Round 3
// 68.723 us; speedup vs baseline: 1.3757x; 1.2461x over previous
//
#include <hip/hip_runtime.h>

// FinalLayer: out[b,m] = bias + sum_c w_c * sum_n y[b,n,c] * exp(-0.5*(x_n-t_m)^2 * exp(-2*sigma_c))
// Shapes: x(B,N_IN) y(B,N_IN,C) t(B,N_OUT) sigma(C) w(C) b(1); out flat B*N_OUT fp32.
//
// Key identity: when sigma is channel-uniform (true for the given inputs),
//   out[b,m] = bias + sum_n ytil[b,n] * exp(a*(x_n-t_m)^2),  ytil[b,n] = sum_c w_c y[b,n,c]
// -> exp count drops 64x (134M -> 2.1M). Uniformity is checked on-device
// (wave __ballot over sigma); a correct per-channel fallback handles the
// general case.
constexpr int Bb   = 4;
constexpr int NIN  = 512;
constexpr int NOUT = 1024;
constexpr int CC   = 64;   // == wavefront size

constexpr int NSPLIT = 8;              // split over n for parallelism (atomic combine)
constexpr int NCHUNK = NIN / NSPLIT;   // 64
constexpr int MPB    = 256;            // m per block (1 per thread)
constexpr int MBLK   = NOUT / MPB;     // 4

// ---- prep: ytil[b*NIN+n] = sum_c w[c]*y[b,n,c] --------------------------
__global__ __launch_bounds__(256) void rbf_prep(
    const float* __restrict__ y, const float* __restrict__ w,
    float* __restrict__ ytil)
{
    const int lane = threadIdx.x & 63;
    const int i    = blockIdx.x * 4 + (threadIdx.x >> 6);  // flat (b,n), 0..2047
    float v = y[(size_t)i * CC + lane] * w[lane];
#pragma unroll
    for (int off = 32; off > 0; off >>= 1) v += __shfl_xor(v, off, 64);
    if (lane == 0) ytil[i] = v;
}

// ---- main ----------------------------------------------------------------
__global__ __launch_bounds__(256) void rbf_main(
    const float* __restrict__ x,     const float* __restrict__ y,
    const float* __restrict__ t,     const float* __restrict__ sigma,
    const float* __restrict__ w,     const float* __restrict__ bias,
    const float* __restrict__ ytil,  float* __restrict__ out)
{
    const int tid   = threadIdx.x;
    const int lane  = tid & 63;
    const int bi    = blockIdx.x;                 // B*MBLK*NSPLIT = 128 blocks
    const int split = bi & (NSPLIT - 1);          // 0..7
    const int mb    = (bi >> 3) & (MBLK - 1);     // 0..3
    const int b     = bi >> 5;                    // 0..3
    const int n0    = split * NCHUNK;

    // device-side sigma-uniformity check (wave-uniform branch)
    const float s0 = sigma[0];
    const bool uni = (__ballot(sigma[lane] == s0) == ~0ull);

    if (uni) {
        // fast path: channel-collapsed. arg = -((x-t)*s)^2 in log2 domain,
        // s = sqrt(0.5*log2(e))*exp(-sigma0) so that s^2 = 0.72134752*exp(-2*sigma0)
        const int   m  = mb * MPB + tid;
        const float s  = 0.84932180f * __expf(-s0);
        const float tm = t[b * NOUT + m] * s;
        const float* __restrict__ xb = x    + b * NIN + n0;  // scalar (s_load) addrs
        const float* __restrict__ yb = ytil + b * NIN + n0;
        float acc = 0.f;
#pragma unroll 8
        for (int n = 0; n < NCHUNK; ++n) {
            const float d = xb[n] * s - tm;
            acc += __builtin_amdgcn_exp2f(-(d * d)) * yb[n];  // neg = free input mod
        }
        atomicAdd(out + b * NOUT + m, acc + (split == 0 ? bias[0] : 0.f));
    } else {
        // general path: lane = channel, each wave covers 64 m values
        const int   wv  = tid >> 6;
        const float kc2 = -0.72134752f * __expf(-2.0f * sigma[lane]);
        const float wc  = w[lane];
        const float* __restrict__ xb = x + b * NIN + n0;
        const float* __restrict__ yb = y + ((size_t)b * NIN + n0) * CC + lane;
        for (int j = 0; j < 64; ++j) {
            const int   m  = mb * MPB + wv * 64 + j;
            const float tm = t[b * NOUT + m];
            float acc = 0.f;
            for (int n = 0; n < NCHUNK; ++n) {
                const float d = xb[n] - tm;
                acc += __builtin_amdgcn_exp2f(d * d * kc2) * yb[(size_t)n * CC];
            }
            float p = acc * wc;
#pragma unroll
            for (int off = 32; off > 0; off >>= 1) p += __shfl_xor(p, off, 64);
            if (lane == 0)
                atomicAdd(out + b * NOUT + m, p + (split == 0 ? bias[0] : 0.f));
        }
    }
}

extern "C" void kernel_launch(void* const* d_in, const int* in_sizes, int n_in,
                              void* d_out, int out_size, void* d_ws, size_t ws_size,
                              hipStream_t stream) {
    const float* x     = (const float*)d_in[0];
    const float* y     = (const float*)d_in[1];
    const float* t     = (const float*)d_in[2];
    const float* sigma = (const float*)d_in[3];
    const float* w     = (const float*)d_in[4];
    const float* bias  = (const float*)d_in[5];
    float* out  = (float*)d_out;
    float* ytil = (float*)d_ws;  // 2048 floats = 8 KB scratch

    // harness re-poisons d_out with 0xAA -> zero it (async, graph-capturable)
    hipMemsetAsync(out, 0, (size_t)out_size * sizeof(float), stream);

    rbf_prep<<<Bb * NIN / 4, 256, 0, stream>>>(y, w, ytil);

    const int grid = Bb * MBLK * NSPLIT;  // 128 blocks
    rbf_main<<<grid, MPB, 0, stream>>>(x, y, t, sigma, w, bias, ytil, out);
}

// Round 4
// 67.411 us; speedup vs baseline: 1.4025x; 1.0195x over previous
//
#include <hip/hip_runtime.h>

// FinalLayer: out[b,m] = bias + sum_c w_c * sum_n y[b,n,c] * exp(-0.5*(x_n-t_m)^2 * exp(-2*sigma_c))
// Shapes: x(B,N_IN) y(B,N_IN,C) t(B,N_OUT) sigma(C) w(C) b(1); out flat B*N_OUT fp32.
//
// sigma is channel-uniform for these inputs -> exact factorization:
//   out[b,m] = bias + sum_n ytil[b,n] * exp2(-((x_n - t_m)*s)^2),
//   ytil[b,n] = sum_c w_c y[b,n,c],  s^2 = 0.5*log2(e)*exp(-2*sigma0)
// Uniformity checked on-device (__ballot); correct per-channel fallback kept.
// Structure: 2 dispatches (prep -> main), no atomics, no memset.
constexpr int Bb   = 4;
constexpr int NIN  = 512;
constexpr int NOUT = 1024;
constexpr int CC   = 64;    // == wavefront size

constexpr int MTILE = 64;          // m per block (main)
constexpr int NGRP  = 4;           // internal n-split (one wave per group)
constexpr int NPER  = NIN / NGRP;  // 128

// ---- prep: ytil[b*NIN+n] = sum_c w[c]*y[b,n,c] ---------------------------
__global__ __launch_bounds__(256) void rbf_prep(
    const float* __restrict__ y, const float* __restrict__ w,
    float* __restrict__ ytil)
{
    const int lane = threadIdx.x & 63;
    const int i    = blockIdx.x * 4 + (threadIdx.x >> 6);  // flat (b,n), 0..2047
    float v = y[(size_t)i * CC + lane] * w[lane];
#pragma unroll
    for (int off = 32; off > 0; off >>= 1) v += __shfl_xor(v, off, 64);
    if (lane == 0) ytil[i] = v;
}

// ---- main: 64 blocks = B x 16 m-tiles; block = 64 m x 4 n-groups ---------
__global__ __launch_bounds__(256) void rbf_main(
    const float* __restrict__ x,     const float* __restrict__ y,
    const float* __restrict__ t,     const float* __restrict__ sigma,
    const float* __restrict__ w,     const float* __restrict__ bias,
    const float* __restrict__ ytil,  float* __restrict__ out)
{
    __shared__ float part[NGRP * MTILE];
    const int tid  = threadIdx.x;
    const int lane = tid & 63;
    const int g    = tid >> 6;               // n-group == wave id
    const int mt   = blockIdx.x & 15;        // m-tile within batch
    const int b    = blockIdx.x >> 4;        // batch
    const int m    = mt * MTILE + lane;

    const float s0  = sigma[0];
    const bool  uni = (__ballot(sigma[lane] == s0) == ~0ull);  // wave-uniform

    if (uni) {
        // s = sqrt(0.5*log2(e))*exp(-sigma0); arg = -((x-t)*s)^2 in log2 domain
        const float s  = 0.84932180f * __expf(-s0);
        const float tm = t[b * NOUT + m] * s;
        const float* __restrict__ xb = x    + b * NIN + g * NPER;  // uniform -> s_load
        const float* __restrict__ yb = ytil + b * NIN + g * NPER;  // uniform -> s_load
        float a0 = 0.f, a1 = 0.f, a2 = 0.f, a3 = 0.f;
#pragma unroll 8
        for (int n = 0; n < NPER; n += 4) {  // 4 accumulators for exp-latency ILP
            const float d0 = xb[n + 0] * s - tm;
            const float d1 = xb[n + 1] * s - tm;
            const float d2 = xb[n + 2] * s - tm;
            const float d3 = xb[n + 3] * s - tm;
            a0 += __builtin_amdgcn_exp2f(-(d0 * d0)) * yb[n + 0];
            a1 += __builtin_amdgcn_exp2f(-(d1 * d1)) * yb[n + 1];
            a2 += __builtin_amdgcn_exp2f(-(d2 * d2)) * yb[n + 2];
            a3 += __builtin_amdgcn_exp2f(-(d3 * d3)) * yb[n + 3];
        }
        part[tid] = (a0 + a1) + (a2 + a3);
        __syncthreads();
        if (g == 0) {
            const float r = (part[lane] + part[64 + lane]) +
                            (part[128 + lane] + part[192 + lane]) + bias[0];
            out[b * NOUT + m] = r;  // coalesced 256B store, no atomics
        }
    } else {
        // general per-channel path: lane = c; wave g handles 16 m values
        const float kc2 = -0.72134752f * __expf(-2.0f * sigma[lane]);
        const float wc  = w[lane];
        const float* __restrict__ xb = x + b * NIN;
        const float* __restrict__ yb = y + (size_t)b * NIN * CC + lane;
        for (int j = 0; j < 16; ++j) {
            const int   mm = mt * MTILE + g * 16 + j;
            const float tm = t[b * NOUT + mm];
            float acc = 0.f;
            for (int n = 0; n < NIN; ++n) {
                const float d = xb[n] - tm;
                acc += __builtin_amdgcn_exp2f(d * d * kc2) * yb[(size_t)n * CC];
            }
            float p = acc * wc;
#pragma unroll
            for (int off = 32; off > 0; off >>= 1) p += __shfl_xor(p, off, 64);
            if (lane == 0) out[b * NOUT + mm] = p + bias[0];
        }
    }
}

extern "C" void kernel_launch(void* const* d_in, const int* in_sizes, int n_in,
                              void* d_out, int out_size, void* d_ws, size_t ws_size,
                              hipStream_t stream) {
    const float* x     = (const float*)d_in[0];
    const float* y     = (const float*)d_in[1];
    const float* t     = (const float*)d_in[2];
    const float* sigma = (const float*)d_in[3];
    const float* w     = (const float*)d_in[4];
    const float* bias  = (const float*)d_in[5];
    float* out  = (float*)d_out;
    float* ytil = (float*)d_ws;  // 2048 floats = 8 KB scratch

    rbf_prep<<<Bb * NIN / 4, 256, 0, stream>>>(y, w, ytil);
    rbf_main<<<Bb * (NOUT / MTILE), 256, 0, stream>>>(x, y, t, sigma, w, bias, ytil, out);
}